// Round 1
// baseline (382.482 us; speedup 1.0000x reference)
//
#include <hip/hip_runtime.h>

#define B_ 4
#define C_ 256
#define L_ 4096
#define NG 32
#define CPG 8

typedef __attribute__((ext_vector_type(8))) __bf16 bf16x8;
typedef __attribute__((ext_vector_type(8))) short s16x8;
typedef __attribute__((ext_vector_type(4))) float f32x4;

__device__ __forceinline__ unsigned short f2bf(float f) {
  unsigned int u = __builtin_bit_cast(unsigned int, f);
  u += 0x7fffu + ((u >> 16) & 1u);
  return (unsigned short)(u >> 16);
}

// ---------------- GroupNorm: stats per (b, group) ----------------
__global__ __launch_bounds__(256) void gn_stats_k(const float* __restrict__ x,
                                                  float* __restrict__ stats) {
  const int bg = blockIdx.x;  // b*NG + g ; group = contiguous CPG*L floats
  const float* base = x + (size_t)bg * (CPG * L_);
  const int t = threadIdx.x;
  float s = 0.f, ss = 0.f;
#pragma unroll
  for (int i = 0; i < 32; ++i) {
    f32x4 v = *(const f32x4*)(base + (size_t)(t + i * 256) * 4);
#pragma unroll
    for (int j = 0; j < 4; ++j) { s += v[j]; ss += v[j] * v[j]; }
  }
#pragma unroll
  for (int d = 1; d < 64; d <<= 1) {
    s += __shfl_xor(s, d, 64);
    ss += __shfl_xor(ss, d, 64);
  }
  __shared__ float red[8];
  if ((t & 63) == 0) { red[(t >> 6) * 2] = s; red[(t >> 6) * 2 + 1] = ss; }
  __syncthreads();
  if (t == 0) {
    float S = red[0] + red[2] + red[4] + red[6];
    float SS = red[1] + red[3] + red[5] + red[7];
    const float inv_n = 1.f / (float)(CPG * L_);
    float mean = S * inv_n;
    float var = SS * inv_n - mean * mean;
    stats[bg * 2] = mean;
    stats[bg * 2 + 1] = rsqrtf(var + 1e-6f);
  }
}

// ------------- GroupNorm apply + transpose -> ht[B*L, C] bf16 -------------
__global__ __launch_bounds__(256) void gn_apply_k(const float* __restrict__ x,
                                                  const float* __restrict__ stats,
                                                  const float* __restrict__ gam,
                                                  const float* __restrict__ bet,
                                                  unsigned short* __restrict__ ht) {
  __shared__ unsigned short tile[64 * 256];  // [l][c]
  const int blk = blockIdx.x;
  const int b = blk >> 6;
  const int l0 = (blk & 63) * 64;
  const int t = threadIdx.x;
  const int c = t;
  const float mean = stats[(b * NG + (c >> 3)) * 2];
  const float rstd = stats[(b * NG + (c >> 3)) * 2 + 1];
  const float sc = rstd * gam[c];
  const float sb = bet[c] - mean * sc;
  const float* row = x + ((size_t)(b * C_ + c)) * L_ + l0;
#pragma unroll
  for (int v = 0; v < 16; ++v) {
    f32x4 f = *(const f32x4*)(row + v * 4);
#pragma unroll
    for (int j = 0; j < 4; ++j) tile[(v * 4 + j) * 256 + c] = f2bf(f[j] * sc + sb);
  }
  __syncthreads();
#pragma unroll
  for (int i = 0; i < 8; ++i) {
    int id = t + i * 256;
    int l = id >> 5, off = id & 31;
    *(s16x8*)(ht + ((size_t)(b * L_) + l0 + l) * 256 + off * 8) =
        *(const s16x8*)(tile + l * 256 + off * 8);
  }
}

// ------------- GEMM-T: Ct[m,n] = sum_k A[m,k]*W[n,k] + bias[n]  (bf16 out) -------------
// A = ht [B*L, 256] bf16 rows; W fp32 [256,256]; out row-major [B*L, 256] bf16.
__global__ __launch_bounds__(256) void gemm_t_k(const unsigned short* __restrict__ A,
                                                const float* __restrict__ W,
                                                const float* __restrict__ bias,
                                                unsigned short* __restrict__ Ct) {
  __shared__ unsigned short Al[64 * 256];  // XOR-swizzled 16B chunks
  __shared__ unsigned short Wl[64 * 256];
  const int m0 = blockIdx.x * 64;
  const int n0 = blockIdx.y * 64;
  const int t = threadIdx.x;
#pragma unroll
  for (int i = 0; i < 8; ++i) {
    int id = t + i * 256;
    int row = id >> 5, c16 = id & 31;
    int pos = (c16 ^ (row & 7)) * 8;
    *(s16x8*)(Al + row * 256 + pos) =
        *(const s16x8*)(A + (size_t)(m0 + row) * 256 + c16 * 8);
    const float* wp = W + (size_t)(n0 + row) * 256 + c16 * 8;
    f32x4 f0 = *(const f32x4*)wp;
    f32x4 f1 = *(const f32x4*)(wp + 4);
    s16x8 wv;
#pragma unroll
    for (int j = 0; j < 4; ++j) {
      wv[j] = (short)f2bf(f0[j]);
      wv[4 + j] = (short)f2bf(f1[j]);
    }
    *(s16x8*)(Wl + row * 256 + pos) = wv;
  }
  __syncthreads();
  const int w = t >> 6, lane = t & 63, l15 = lane & 15, q = lane >> 4;
  bf16x8 af[8];
#pragma unroll
  for (int kf = 0; kf < 8; ++kf) {
    int row = w * 16 + l15;
    af[kf] = *(const bf16x8*)(Al + row * 256 + (((kf * 4 + q) ^ (row & 7)) * 8));
  }
  f32x4 acc[4];
#pragma unroll
  for (int nf = 0; nf < 4; ++nf) {
    f32x4 cacc = {0.f, 0.f, 0.f, 0.f};
#pragma unroll
    for (int kf = 0; kf < 8; ++kf) {
      int row = nf * 16 + l15;
      bf16x8 bf = *(const bf16x8*)(Wl + row * 256 + (((kf * 4 + q) ^ (row & 7)) * 8));
      cacc = __builtin_amdgcn_mfma_f32_16x16x32_bf16(af[kf], bf, cacc, 0, 0, 0);
    }
    acc[nf] = cacc;
  }
#pragma unroll
  for (int nf = 0; nf < 4; ++nf) {
    const int n = n0 + nf * 16 + l15;
    const float bs = bias[n];
#pragma unroll
    for (int r = 0; r < 4; ++r) {
      const int m = m0 + w * 16 + q * 4 + r;
      Ct[(size_t)m * 256 + n] = f2bf(acc[nf][r] + bs);
    }
  }
}

// ------------- GEMM-N: out[o,i] = sum_k W[o,k]*X[b*L+i,k] + bias[o] -------------
// MODE 0: bf16 out to natural [B, C, L].  MODE 1: fp32 out + residual x.
template <int MODE>
__global__ __launch_bounds__(256) void gemm_n_k(const unsigned short* __restrict__ X,
                                                const float* __restrict__ W,
                                                const float* __restrict__ bias,
                                                const float* __restrict__ xres,
                                                void* __restrict__ outv) {
  __shared__ unsigned short Wl[64 * 256];
  __shared__ unsigned short Xl[64 * 256];
  const int i0 = blockIdx.x * 64;
  const int o0 = blockIdx.y * 64;
  const int b = blockIdx.z;
  const int t = threadIdx.x;
#pragma unroll
  for (int i = 0; i < 8; ++i) {
    int id = t + i * 256;
    int row = id >> 5, c16 = id & 31;
    int pos = (c16 ^ (row & 7)) * 8;
    const float* wp = W + (size_t)(o0 + row) * 256 + c16 * 8;
    f32x4 f0 = *(const f32x4*)wp;
    f32x4 f1 = *(const f32x4*)(wp + 4);
    s16x8 wv;
#pragma unroll
    for (int j = 0; j < 4; ++j) {
      wv[j] = (short)f2bf(f0[j]);
      wv[4 + j] = (short)f2bf(f1[j]);
    }
    *(s16x8*)(Wl + row * 256 + pos) = wv;
    *(s16x8*)(Xl + row * 256 + pos) =
        *(const s16x8*)(X + ((size_t)(b * L_) + i0 + row) * 256 + c16 * 8);
  }
  __syncthreads();
  const int w = t >> 6, lane = t & 63, l15 = lane & 15, q = lane >> 4;
  bf16x8 af[8];
#pragma unroll
  for (int kf = 0; kf < 8; ++kf) {
    int row = w * 16 + l15;
    af[kf] = *(const bf16x8*)(Wl + row * 256 + (((kf * 4 + q) ^ (row & 7)) * 8));
  }
  f32x4 acc[4];
#pragma unroll
  for (int nf = 0; nf < 4; ++nf) {
    f32x4 cacc = {0.f, 0.f, 0.f, 0.f};
#pragma unroll
    for (int kf = 0; kf < 8; ++kf) {
      int row = nf * 16 + l15;
      bf16x8 bf = *(const bf16x8*)(Xl + row * 256 + (((kf * 4 + q) ^ (row & 7)) * 8));
      cacc = __builtin_amdgcn_mfma_f32_16x16x32_bf16(af[kf], bf, cacc, 0, 0, 0);
    }
    acc[nf] = cacc;
  }
#pragma unroll
  for (int nf = 0; nf < 4; ++nf) {
    const int i = i0 + nf * 16 + l15;
#pragma unroll
    for (int r = 0; r < 4; ++r) {
      const int o = o0 + w * 16 + q * 4 + r;
      const size_t idx = ((size_t)(b * C_ + o)) * L_ + i;
      float v = acc[nf][r] + bias[o];
      if (MODE == 0) {
        ((unsigned short*)outv)[idx] = f2bf(v);
      } else {
        ((float*)outv)[idx] = v + xres[idx];
      }
    }
  }
}

// ------------- Flash attention: O[B*L, C] bf16 -------------
// Qt,Kt: [B*L, C] bf16 rows; Vn: [B, C, L] bf16 natural.
__global__ __launch_bounds__(256) void attn_k(const unsigned short* __restrict__ Qt,
                                              const unsigned short* __restrict__ Kt,
                                              const unsigned short* __restrict__ Vn,
                                              unsigned short* __restrict__ O) {
  __shared__ unsigned short Kl[32 * 256];   // [j][c], XOR-swizzled chunks
  __shared__ unsigned short Vl[256 * 40];   // [c][j], padded rows (32+8)
  __shared__ unsigned short Pl[4 * 16 * 40];  // per-wave [16 q][32 j], padded
  const int bid = blockIdx.x;
  const int b = bid >> 6;
  const int i0 = (bid & 63) * 64;
  const int t = threadIdx.x;
  const int w = t >> 6, lane = t & 63, l15 = lane & 15, q = lane >> 4;

  bf16x8 qf[8];
  {
    const size_t qbase = ((size_t)(b * L_) + i0 + w * 16 + l15) * 256;
#pragma unroll
    for (int kf = 0; kf < 8; ++kf)
      qf[kf] = *(const bf16x8*)(Qt + qbase + kf * 32 + q * 8);
  }
  f32x4 oacc[16];
#pragma unroll
  for (int cf = 0; cf < 16; ++cf) oacc[cf] = {0.f, 0.f, 0.f, 0.f};
  float mrun[4] = {-3.0e38f, -3.0e38f, -3.0e38f, -3.0e38f};
  float lrun[4] = {0.f, 0.f, 0.f, 0.f};
  const float scale = 0.0625f;  // C^-0.5

  for (int j0 = 0; j0 < L_; j0 += 32) {
    __syncthreads();
#pragma unroll
    for (int i = 0; i < 4; ++i) {
      int id = t + i * 256;
      int row = id >> 5, c16 = id & 31;
      *(s16x8*)(Kl + row * 256 + ((c16 ^ (row & 7)) * 8)) =
          *(const s16x8*)(Kt + ((size_t)(b * L_) + j0 + row) * 256 + c16 * 8);
    }
#pragma unroll
    for (int i = 0; i < 4; ++i) {
      int id = t + i * 256;
      int c = id >> 2, off = id & 3;
      *(s16x8*)(Vl + c * 40 + off * 8) =
          *(const s16x8*)(Vn + ((size_t)(b * C_ + c)) * L_ + j0 + off * 8);
    }
    __syncthreads();

    f32x4 s[2];
#pragma unroll
    for (int nf = 0; nf < 2; ++nf) {
      f32x4 cacc = {0.f, 0.f, 0.f, 0.f};
#pragma unroll
      for (int kf = 0; kf < 8; ++kf) {
        int row = nf * 16 + l15;
        bf16x8 bf = *(const bf16x8*)(Kl + row * 256 + (((kf * 4 + q) ^ (row & 7)) * 8));
        cacc = __builtin_amdgcn_mfma_f32_16x16x32_bf16(qf[kf], bf, cacc, 0, 0, 0);
      }
#pragma unroll
      for (int r = 0; r < 4; ++r) s[nf][r] = cacc[r] * scale;
    }
    // online softmax; row of query = q*4 + r, cols spread over 16 lanes of group q
    float mx[4];
#pragma unroll
    for (int r = 0; r < 4; ++r) mx[r] = fmaxf(s[0][r], s[1][r]);
#pragma unroll
    for (int d = 1; d < 16; d <<= 1)
#pragma unroll
      for (int r = 0; r < 4; ++r) mx[r] = fmaxf(mx[r], __shfl_xor(mx[r], d, 64));
    float alpha[4];
#pragma unroll
    for (int r = 0; r < 4; ++r) {
      float mn = fmaxf(mrun[r], mx[r]);
      alpha[r] = __expf(mrun[r] - mn);
      mrun[r] = mn;
    }
    float sm[4];
#pragma unroll
    for (int r = 0; r < 4; ++r) {
      s[0][r] = __expf(s[0][r] - mrun[r]);
      s[1][r] = __expf(s[1][r] - mrun[r]);
      sm[r] = s[0][r] + s[1][r];
    }
#pragma unroll
    for (int d = 1; d < 16; d <<= 1)
#pragma unroll
      for (int r = 0; r < 4; ++r) sm[r] += __shfl_xor(sm[r], d, 64);
#pragma unroll
    for (int r = 0; r < 4; ++r) lrun[r] = lrun[r] * alpha[r] + sm[r];
#pragma unroll
    for (int cf = 0; cf < 16; ++cf)
#pragma unroll
      for (int r = 0; r < 4; ++r) oacc[cf][r] *= alpha[r];
    // P -> per-wave LDS (C/D layout -> A layout round trip)
#pragma unroll
    for (int nf = 0; nf < 2; ++nf)
#pragma unroll
      for (int r = 0; r < 4; ++r)
        Pl[w * 640 + (q * 4 + r) * 40 + nf * 16 + l15] = f2bf(s[nf][r]);
    bf16x8 af = *(const bf16x8*)(Pl + w * 640 + l15 * 40 + q * 8);
#pragma unroll
    for (int cf = 0; cf < 16; ++cf) {
      bf16x8 bf = *(const bf16x8*)(Vl + (cf * 16 + l15) * 40 + q * 8);
      oacc[cf] = __builtin_amdgcn_mfma_f32_16x16x32_bf16(af, bf, oacc[cf], 0, 0, 0);
    }
  }
#pragma unroll
  for (int cf = 0; cf < 16; ++cf) {
#pragma unroll
    for (int r = 0; r < 4; ++r) {
      float v = oacc[cf][r] / lrun[r];
      O[((size_t)(b * L_) + i0 + w * 16 + q * 4 + r) * 256 + cf * 16 + l15] = f2bf(v);
    }
  }
}

extern "C" void kernel_launch(void* const* d_in, const int* in_sizes, int n_in,
                              void* d_out, int out_size, void* d_ws, size_t ws_size,
                              hipStream_t stream) {
  const float* x = (const float*)d_in[0];
  const float* norm_g = (const float*)d_in[1];
  const float* norm_b = (const float*)d_in[2];
  const float* q_w = (const float*)d_in[3];
  const float* q_b = (const float*)d_in[4];
  const float* k_w = (const float*)d_in[5];
  const float* k_b = (const float*)d_in[6];
  const float* v_w = (const float*)d_in[7];
  const float* v_b = (const float*)d_in[8];
  const float* p_w = (const float*)d_in[9];
  const float* p_b = (const float*)d_in[10];
  float* out = (float*)d_out;

  char* ws = (char*)d_ws;
  const size_t NTOK = (size_t)B_ * L_ * C_;  // 4,194,304 elements
  float* stats = (float*)ws;                                   // 1 KB
  unsigned short* ht = (unsigned short*)(ws + 1024);           // 8 MB
  unsigned short* qt = ht + NTOK;
  unsigned short* kt = qt + NTOK;
  unsigned short* vn = kt + NTOK;
  unsigned short* ob = vn + NTOK;
  (void)in_sizes; (void)n_in; (void)out_size; (void)ws_size;

  gn_stats_k<<<B_ * NG, 256, 0, stream>>>(x, stats);
  gn_apply_k<<<B_ * (L_ / 64), 256, 0, stream>>>(x, stats, norm_g, norm_b, ht);
  gemm_t_k<<<dim3((B_ * L_) / 64, C_ / 64), 256, 0, stream>>>(ht, q_w, q_b, qt);
  gemm_t_k<<<dim3((B_ * L_) / 64, C_ / 64), 256, 0, stream>>>(ht, k_w, k_b, kt);
  gemm_n_k<0><<<dim3(L_ / 64, C_ / 64, B_), 256, 0, stream>>>(ht, v_w, v_b, nullptr, vn);
  attn_k<<<B_ * (L_ / 64), 256, 0, stream>>>(qt, kt, vn, ob);
  gemm_n_k<1><<<dim3(L_ / 64, C_ / 64, B_), 256, 0, stream>>>(ob, p_w, p_b, x, out);
}

// Round 2
// 282.284 us; speedup vs baseline: 1.3550x; 1.3550x over previous
//
#include <hip/hip_runtime.h>

#define B_ 4
#define C_ 256
#define L_ 4096
#define NG 32
#define CPG 8
#define BL (B_ * L_)               // 16384 token rows
#define KPART 2
#define KEYS_PP (L_ / KPART)       // 2048 keys per partition
#define QLOG2E 0.09016844f         // C^-0.5 * log2(e), folded into q_w/q_b

typedef __attribute__((ext_vector_type(8))) __bf16 bf16x8;
typedef __attribute__((ext_vector_type(8))) short s16x8;
typedef __attribute__((ext_vector_type(4))) float f32x4;

__device__ __forceinline__ unsigned short f2bf(float f) {
  unsigned int u = __builtin_bit_cast(unsigned int, f);
  u += 0x7fffu + ((u >> 16) & 1u);
  return (unsigned short)(u >> 16);
}
__device__ __forceinline__ float bf2f(unsigned short u) {
  unsigned int v = ((unsigned int)u) << 16;
  return __builtin_bit_cast(float, v);
}
#if __has_builtin(__builtin_amdgcn_exp2f)
#define EXP2F(x) __builtin_amdgcn_exp2f(x)
#else
#define EXP2F(x) exp2f(x)
#endif

// ---------------- wcvt: f32 weights -> bf16 (q_w pre-scaled), scaled q bias --------
__global__ __launch_bounds__(256) void wcvt_k(const float* __restrict__ qw,
                                              const float* __restrict__ kw,
                                              const float* __restrict__ vw,
                                              const float* __restrict__ pw,
                                              const float* __restrict__ qb,
                                              unsigned short* __restrict__ wq,
                                              unsigned short* __restrict__ wk,
                                              unsigned short* __restrict__ wv,
                                              unsigned short* __restrict__ wp,
                                              float* __restrict__ qbs) {
  const int m = blockIdx.x >> 5;
  const int blk = blockIdx.x & 31;
  const float* src = (m == 0) ? qw : (m == 1) ? kw : (m == 2) ? vw : pw;
  unsigned short* dst = (m == 0) ? wq : (m == 1) ? wk : (m == 2) ? wv : wp;
  const float sc = (m == 0) ? QLOG2E : 1.0f;
  const int base = (blk * 256 + threadIdx.x) * 8;
  f32x4 a = *(const f32x4*)(src + base);
  f32x4 b = *(const f32x4*)(src + base + 4);
  s16x8 o;
#pragma unroll
  for (int j = 0; j < 4; ++j) {
    o[j] = (short)f2bf(a[j] * sc);
    o[4 + j] = (short)f2bf(b[j] * sc);
  }
  *(s16x8*)(dst + base) = o;
  if (m == 0 && blk == 0) qbs[threadIdx.x] = qb[threadIdx.x] * QLOG2E;
}

// ---------------- GroupNorm: stats per (b, group) ----------------
__global__ __launch_bounds__(256) void gn_stats_k(const float* __restrict__ x,
                                                  float* __restrict__ stats) {
  const int bg = blockIdx.x;
  const float* base = x + (size_t)bg * (CPG * L_);
  const int t = threadIdx.x;
  float s = 0.f, ss = 0.f;
#pragma unroll
  for (int i = 0; i < 32; ++i) {
    f32x4 v = *(const f32x4*)(base + (size_t)(t + i * 256) * 4);
#pragma unroll
    for (int j = 0; j < 4; ++j) { s += v[j]; ss += v[j] * v[j]; }
  }
#pragma unroll
  for (int d = 1; d < 64; d <<= 1) {
    s += __shfl_xor(s, d, 64);
    ss += __shfl_xor(ss, d, 64);
  }
  __shared__ float red[8];
  if ((t & 63) == 0) { red[(t >> 6) * 2] = s; red[(t >> 6) * 2 + 1] = ss; }
  __syncthreads();
  if (t == 0) {
    float S = red[0] + red[2] + red[4] + red[6];
    float SS = red[1] + red[3] + red[5] + red[7];
    const float inv_n = 1.f / (float)(CPG * L_);
    float mean = S * inv_n;
    float var = SS * inv_n - mean * mean;
    stats[bg * 2] = mean;
    stats[bg * 2 + 1] = rsqrtf(var + 1e-6f);
  }
}

// ------------- GroupNorm apply + transpose -> ht[B*L, C] bf16 -------------
__global__ __launch_bounds__(256) void gn_apply_k(const float* __restrict__ x,
                                                  const float* __restrict__ stats,
                                                  const float* __restrict__ gam,
                                                  const float* __restrict__ bet,
                                                  unsigned short* __restrict__ ht) {
  __shared__ unsigned short tile[64 * 256];
  const int blk = blockIdx.x;
  const int b = blk >> 6;
  const int l0 = (blk & 63) * 64;
  const int t = threadIdx.x;
  const int c = t;
  const float mean = stats[(b * NG + (c >> 3)) * 2];
  const float rstd = stats[(b * NG + (c >> 3)) * 2 + 1];
  const float sc = rstd * gam[c];
  const float sb = bet[c] - mean * sc;
  const float* row = x + ((size_t)(b * C_ + c)) * L_ + l0;
#pragma unroll
  for (int v = 0; v < 16; ++v) {
    f32x4 f = *(const f32x4*)(row + v * 4);
#pragma unroll
    for (int j = 0; j < 4; ++j) tile[(v * 4 + j) * 256 + c] = f2bf(f[j] * sc + sb);
  }
  __syncthreads();
#pragma unroll
  for (int i = 0; i < 8; ++i) {
    int id = t + i * 256;
    int l = id >> 5, off = id & 31;
    *(s16x8*)(ht + ((size_t)(b * L_) + l0 + l) * 256 + off * 8) =
        *(const s16x8*)(tile + l * 256 + off * 8);
  }
}

// ------------- GEMM-T: Ct[m,n] = sum_k A[m,k]*W[n,k] + bias[n]  (bf16 out) -------------
__global__ __launch_bounds__(256) void gemm_t_k(const unsigned short* __restrict__ A,
                                                const unsigned short* __restrict__ W,
                                                const float* __restrict__ bias,
                                                unsigned short* __restrict__ Ct) {
  __shared__ unsigned short Al[64 * 256];
  __shared__ unsigned short Wl[64 * 256];
  const int m0 = blockIdx.x * 64;
  const int n0 = blockIdx.y * 64;
  const int t = threadIdx.x;
#pragma unroll
  for (int i = 0; i < 8; ++i) {
    int id = t + i * 256;
    int row = id >> 5, c16 = id & 31;
    int pos = (c16 ^ (row & 7)) * 8;
    *(s16x8*)(Al + row * 256 + pos) =
        *(const s16x8*)(A + (size_t)(m0 + row) * 256 + c16 * 8);
    *(s16x8*)(Wl + row * 256 + pos) =
        *(const s16x8*)(W + (size_t)(n0 + row) * 256 + c16 * 8);
  }
  __syncthreads();
  const int w = t >> 6, lane = t & 63, l15 = lane & 15, q = lane >> 4;
  bf16x8 af[8];
#pragma unroll
  for (int kf = 0; kf < 8; ++kf) {
    int row = w * 16 + l15;
    af[kf] = *(const bf16x8*)(Al + row * 256 + (((kf * 4 + q) ^ (row & 7)) * 8));
  }
  f32x4 acc[4];
#pragma unroll
  for (int nf = 0; nf < 4; ++nf) {
    f32x4 cacc = {0.f, 0.f, 0.f, 0.f};
#pragma unroll
    for (int kf = 0; kf < 8; ++kf) {
      int row = nf * 16 + l15;
      bf16x8 bf = *(const bf16x8*)(Wl + row * 256 + (((kf * 4 + q) ^ (row & 7)) * 8));
      cacc = __builtin_amdgcn_mfma_f32_16x16x32_bf16(af[kf], bf, cacc, 0, 0, 0);
    }
    acc[nf] = cacc;
  }
#pragma unroll
  for (int nf = 0; nf < 4; ++nf) {
    const int n = n0 + nf * 16 + l15;
    const float bs = bias[n];
#pragma unroll
    for (int r = 0; r < 4; ++r) {
      const int m = m0 + w * 16 + q * 4 + r;
      Ct[(size_t)m * 256 + n] = f2bf(acc[nf][r] + bs);
    }
  }
}

// ------------- GEMM-N: out[o,i] = sum_k W[o,k]*X[b*L+i,k] + bias[o] -------------
// MODE 0: bf16 out to chunked [B][L/8][C][8].  MODE 1: fp32 out + residual x.
template <int MODE>
__global__ __launch_bounds__(256) void gemm_n_k(const unsigned short* __restrict__ X,
                                                const unsigned short* __restrict__ W,
                                                const float* __restrict__ bias,
                                                const float* __restrict__ xres,
                                                void* __restrict__ outv) {
  __shared__ unsigned short Wl[64 * 256];
  __shared__ unsigned short Xl[64 * 256];
  const int i0 = blockIdx.x * 64;
  const int o0 = blockIdx.y * 64;
  const int b = blockIdx.z;
  const int t = threadIdx.x;
#pragma unroll
  for (int i = 0; i < 8; ++i) {
    int id = t + i * 256;
    int row = id >> 5, c16 = id & 31;
    int pos = (c16 ^ (row & 7)) * 8;
    *(s16x8*)(Wl + row * 256 + pos) =
        *(const s16x8*)(W + (size_t)(o0 + row) * 256 + c16 * 8);
    *(s16x8*)(Xl + row * 256 + pos) =
        *(const s16x8*)(X + ((size_t)(b * L_) + i0 + row) * 256 + c16 * 8);
  }
  __syncthreads();
  const int w = t >> 6, lane = t & 63, l15 = lane & 15, q = lane >> 4;
  bf16x8 af[8];
#pragma unroll
  for (int kf = 0; kf < 8; ++kf) {
    int row = w * 16 + l15;
    af[kf] = *(const bf16x8*)(Wl + row * 256 + (((kf * 4 + q) ^ (row & 7)) * 8));
  }
  f32x4 acc[4];
#pragma unroll
  for (int nf = 0; nf < 4; ++nf) {
    f32x4 cacc = {0.f, 0.f, 0.f, 0.f};
#pragma unroll
    for (int kf = 0; kf < 8; ++kf) {
      int row = nf * 16 + l15;
      bf16x8 bf = *(const bf16x8*)(Xl + row * 256 + (((kf * 4 + q) ^ (row & 7)) * 8));
      cacc = __builtin_amdgcn_mfma_f32_16x16x32_bf16(af[kf], bf, cacc, 0, 0, 0);
    }
    acc[nf] = cacc;
  }
#pragma unroll
  for (int nf = 0; nf < 4; ++nf) {
    const int i = i0 + nf * 16 + l15;
#pragma unroll
    for (int r = 0; r < 4; ++r) {
      const int o = o0 + w * 16 + q * 4 + r;
      float v = acc[nf][r] + bias[o];
      if (MODE == 0) {
        // chunked: [b][i>>3][o][i&7]
        ((unsigned short*)outv)[(((size_t)(b * (L_ / 8) + (i >> 3))) * 256 + o) * 8 + (i & 7)] =
            f2bf(v);
      } else {
        const size_t idx = ((size_t)(b * C_ + o)) * L_ + i;
        ((float*)outv)[idx] = v + xres[idx];
      }
    }
  }
}

// ------------- Flash attention (key-partitioned): partial O + (m,l) -------------
// Qt,Kt: [B*L, C] bf16 rows (Q pre-scaled by QLOG2E); Vc: chunked [B][L/8][C][8].
__global__ __launch_bounds__(256, 2) void attn_k(const unsigned short* __restrict__ Qt,
                                                 const unsigned short* __restrict__ Kt,
                                                 const unsigned short* __restrict__ Vc,
                                                 unsigned short* __restrict__ Opart,
                                                 float* __restrict__ ml) {
  __shared__ unsigned short Kl[32 * 264];      // [j][c], rows padded +8 shorts
  __shared__ unsigned short Vl[4 * 256 * 8];   // [jchunk][c][8]
  __shared__ unsigned short Pl[4 * 16 * 40];   // per-wave [16 q][32 j], padded +8
  const int bid = blockIdx.x;
  const int part = bid >> 8;                   // 0..KPART-1
  const int b = (bid >> 6) & 3;
  const int i0 = (bid & 63) * 64;
  const int t = threadIdx.x;
  const int w = t >> 6, lane = t & 63, l15 = lane & 15, q = lane >> 4;

  bf16x8 qf[8];
  {
    const size_t qbase = ((size_t)(b * L_) + i0 + w * 16 + l15) * 256;
#pragma unroll
    for (int kf = 0; kf < 8; ++kf)
      qf[kf] = *(const bf16x8*)(Qt + qbase + kf * 32 + q * 8);
  }
  f32x4 oacc[16];
#pragma unroll
  for (int cf = 0; cf < 16; ++cf) oacc[cf] = {0.f, 0.f, 0.f, 0.f};
  float mrun[4] = {-1.0e30f, -1.0e30f, -1.0e30f, -1.0e30f};
  float lrun[4] = {0.f, 0.f, 0.f, 0.f};
  const int kbase = part * KEYS_PP;

  for (int j0 = 0; j0 < KEYS_PP; j0 += 32) {
    __syncthreads();
#pragma unroll
    for (int i = 0; i < 4; ++i) {   // K stage: 32 rows x 256ch
      int id = t + i * 256;
      int row = id >> 5, c16 = id & 31;
      *(s16x8*)(Kl + row * 264 + c16 * 8) =
          *(const s16x8*)(Kt + ((size_t)(b * L_) + kbase + j0 + row) * 256 + c16 * 8);
    }
    {
      const size_t vb = (size_t)(b * (L_ / 8)) + ((kbase + j0) >> 3);
#pragma unroll
      for (int i = 0; i < 4; ++i)   // V stage: 4 key-chunks x 256ch, fully coalesced
        *(s16x8*)(Vl + (i * 256 + t) * 8) = *(const s16x8*)(Vc + ((vb + i) * 256 + t) * 8);
    }
    __syncthreads();

    f32x4 s0 = {0.f, 0.f, 0.f, 0.f}, s1 = {0.f, 0.f, 0.f, 0.f};
#pragma unroll
    for (int kf = 0; kf < 8; ++kf) {
      bf16x8 b0 = *(const bf16x8*)(Kl + l15 * 264 + (kf * 4 + q) * 8);
      bf16x8 b1 = *(const bf16x8*)(Kl + (16 + l15) * 264 + (kf * 4 + q) * 8);
      s0 = __builtin_amdgcn_mfma_f32_16x16x32_bf16(qf[kf], b0, s0, 0, 0, 0);
      s1 = __builtin_amdgcn_mfma_f32_16x16x32_bf16(qf[kf], b1, s1, 0, 0, 0);
    }
    // online softmax in log2 domain (scale folded into Q)
    float mx[4], alpha[4], sm[4];
#pragma unroll
    for (int r = 0; r < 4; ++r) mx[r] = fmaxf(s0[r], s1[r]);
#pragma unroll
    for (int d = 1; d < 16; d <<= 1)
#pragma unroll
      for (int r = 0; r < 4; ++r) mx[r] = fmaxf(mx[r], __shfl_xor(mx[r], d, 64));
    int resc = 0;
#pragma unroll
    for (int r = 0; r < 4; ++r) {
      float mn = fmaxf(mrun[r], mx[r]);
      alpha[r] = EXP2F(mrun[r] - mn);
      mrun[r] = mn;
      resc |= (alpha[r] != 1.0f);
    }
#pragma unroll
    for (int r = 0; r < 4; ++r) {
      s0[r] = EXP2F(s0[r] - mrun[r]);
      s1[r] = EXP2F(s1[r] - mrun[r]);
      sm[r] = s0[r] + s1[r];
    }
#pragma unroll
    for (int d = 1; d < 16; d <<= 1)
#pragma unroll
      for (int r = 0; r < 4; ++r) sm[r] += __shfl_xor(sm[r], d, 64);
#pragma unroll
    for (int r = 0; r < 4; ++r) lrun[r] = lrun[r] * alpha[r] + sm[r];
    if (__any(resc)) {
#pragma unroll
      for (int cf = 0; cf < 16; ++cf)
#pragma unroll
        for (int r = 0; r < 4; ++r) oacc[cf][r] *= alpha[r];
    }
    // P: C-layout -> LDS -> A-layout
#pragma unroll
    for (int r = 0; r < 4; ++r) {
      Pl[w * 640 + (q * 4 + r) * 40 + l15] = f2bf(s0[r]);
      Pl[w * 640 + (q * 4 + r) * 40 + 16 + l15] = f2bf(s1[r]);
    }
    bf16x8 af = *(const bf16x8*)(Pl + w * 640 + l15 * 40 + q * 8);
#pragma unroll
    for (int cf = 0; cf < 16; ++cf) {
      bf16x8 bv = *(const bf16x8*)(Vl + (q * 256 + cf * 16 + l15) * 8);
      oacc[cf] = __builtin_amdgcn_mfma_f32_16x16x32_bf16(af, bv, oacc[cf], 0, 0, 0);
    }
  }
  const int grow0 = b * L_ + i0 + w * 16;
#pragma unroll
  for (int cf = 0; cf < 16; ++cf)
#pragma unroll
    for (int r = 0; r < 4; ++r)
      Opart[((size_t)part * BL + grow0 + q * 4 + r) * 256 + cf * 16 + l15] =
          f2bf(oacc[cf][r]);
  if (l15 == 0) {
#pragma unroll
    for (int r = 0; r < 4; ++r) {
      const size_t grow = (size_t)part * BL + grow0 + q * 4 + r;
      ml[grow * 2] = mrun[r];
      ml[grow * 2 + 1] = lrun[r];
    }
  }
}

// ------------- merge KPART partials -> Om [B*L, C] bf16 -------------
__global__ __launch_bounds__(256) void merge_k(const unsigned short* __restrict__ Op,
                                               const float* __restrict__ ml,
                                               unsigned short* __restrict__ Om) {
  const int row = blockIdx.x * 8 + (threadIdx.x >> 5);
  const int c8 = threadIdx.x & 31;
  float m0 = ml[(size_t)row * 2], l0 = ml[(size_t)row * 2 + 1];
  float m1 = ml[((size_t)BL + row) * 2], l1 = ml[((size_t)BL + row) * 2 + 1];
  float M = fmaxf(m0, m1);
  float a0 = EXP2F(m0 - M), a1 = EXP2F(m1 - M);
  float inv = 1.0f / (a0 * l0 + a1 * l1);
  a0 *= inv; a1 *= inv;
  s16x8 v0 = *(const s16x8*)(Op + (size_t)row * 256 + c8 * 8);
  s16x8 v1 = *(const s16x8*)(Op + ((size_t)BL + row) * 256 + c8 * 8);
  s16x8 o;
#pragma unroll
  for (int j = 0; j < 8; ++j)
    o[j] = (short)f2bf(a0 * bf2f((unsigned short)v0[j]) + a1 * bf2f((unsigned short)v1[j]));
  *(s16x8*)(Om + (size_t)row * 256 + c8 * 8) = o;
}

extern "C" void kernel_launch(void* const* d_in, const int* in_sizes, int n_in,
                              void* d_out, int out_size, void* d_ws, size_t ws_size,
                              hipStream_t stream) {
  const float* x = (const float*)d_in[0];
  const float* norm_g = (const float*)d_in[1];
  const float* norm_b = (const float*)d_in[2];
  const float* q_w = (const float*)d_in[3];
  const float* q_b = (const float*)d_in[4];
  const float* k_w = (const float*)d_in[5];
  const float* k_b = (const float*)d_in[6];
  const float* v_w = (const float*)d_in[7];
  const float* v_b = (const float*)d_in[8];
  const float* p_w = (const float*)d_in[9];
  const float* p_b = (const float*)d_in[10];
  float* out = (float*)d_out;
  (void)in_sizes; (void)n_in; (void)out_size; (void)ws_size;

  char* ws = (char*)d_ws;
  const size_t MB = 1u << 20;
  float* stats = (float*)ws;                              // 1 KB
  float* qbs = (float*)(ws + 1024);                       // 1 KB
  unsigned short* wq = (unsigned short*)(ws + 4096);      // 128 KB each
  unsigned short* wk = wq + 65536;
  unsigned short* wv = wk + 65536;
  unsigned short* wp = wv + 65536;
  unsigned short* ht = (unsigned short*)(ws + 1 * MB);    // 8 MB
  unsigned short* qt = (unsigned short*)(ws + 9 * MB);    // 8 MB
  unsigned short* kt = (unsigned short*)(ws + 17 * MB);   // 8 MB (later: merged O)
  unsigned short* vn = (unsigned short*)(ws + 25 * MB);   // 8 MB chunked V
  float* ml = (float*)(ws + 33 * MB);                     // 256 KB
  unsigned short* opart = (unsigned short*)d_out;         // 2 x 8 MB bf16 partials

  wcvt_k<<<128, 256, 0, stream>>>(q_w, k_w, v_w, p_w, q_b, wq, wk, wv, wp, qbs);
  gn_stats_k<<<B_ * NG, 256, 0, stream>>>(x, stats);
  gn_apply_k<<<B_ * (L_ / 64), 256, 0, stream>>>(x, stats, norm_g, norm_b, ht);
  gemm_t_k<<<dim3((B_ * L_) / 64, C_ / 64), 256, 0, stream>>>(ht, wq, qbs, qt);
  gemm_t_k<<<dim3((B_ * L_) / 64, C_ / 64), 256, 0, stream>>>(ht, wk, k_b, kt);
  gemm_n_k<0><<<dim3(L_ / 64, C_ / 64, B_), 256, 0, stream>>>(ht, wv, v_b, nullptr, vn);
  attn_k<<<KPART * B_ * (L_ / 64), 256, 0, stream>>>(qt, kt, vn, opart, ml);
  merge_k<<<BL / 8, 256, 0, stream>>>(opart, ml, kt);
  gemm_n_k<1><<<dim3(L_ / 64, C_ / 64, B_), 256, 0, stream>>>(kt, wp, p_b, x, out);
}